// Round 16
// baseline (42.372 us; speedup 1.0000x reference)
//
#include <hip/hip_runtime.h>
#include <hip/hip_bf16.h>

#define EPS 1e-6f

typedef __attribute__((ext_vector_type(4))) float f32x4;

// pack 4 floats into 4 fp8-e4m3 bytes (k-order: x->byte0 .. w->byte3)
__device__ inline unsigned int pack_fp8x4(float x, float y, float z, float w) {
  int r = 0;
  r = __builtin_amdgcn_cvt_pk_fp8_f32(x, y, r, false);  // bytes 0,1
  r = __builtin_amdgcn_cvt_pk_fp8_f32(z, w, r, true);   // bytes 2,3
  return (unsigned int)r;
}

// ---------------------------------------------------------------------------
// Kernel A (round-15 winner, unchanged): ONE WAVE PER SPEAKER.
// 256 blocks x 256 threads (4 speakers/block, lane owns 12 dims).
// Writes a8 (fp8 normalized rows), c8 (fp8 normalized centroids),
// simown (exact fp32), zeroes rowsum and out[0].
// ---------------------------------------------------------------------------
__global__ void __launch_bounds__(256) ge2e_pre(
    const float* __restrict__ dv, unsigned int* __restrict__ a8u,
    unsigned int* __restrict__ c8u, float* __restrict__ simown,
    float* __restrict__ rowsum, float* __restrict__ out) {
  const int t = threadIdx.x;
  const int wave = t >> 6, lane = t & 63;
  const int n = blockIdx.x * 4 + wave;           // speaker 0..1023
  const int gid = blockIdx.x * 256 + t;
  if (gid < 10240) rowsum[gid] = 0.f;            // accumulated by gemm atomics
  if (gid == 0) out[0] = 0.f;
  const float* base = dv + (size_t)n * 7680 + lane * 12;

  f32x4 v[10][3];
  f32x4 s4[3] = {{0.f, 0.f, 0.f, 0.f}, {0.f, 0.f, 0.f, 0.f}, {0.f, 0.f, 0.f, 0.f}};
#pragma unroll
  for (int m = 0; m < 10; ++m)
#pragma unroll
    for (int j = 0; j < 3; ++j) {
      v[m][j] = *reinterpret_cast<const f32x4*>(base + m * 768 + j * 4);
      s4[j] += v[m][j];
    }
  float part[20];
#pragma unroll
  for (int m = 0; m < 10; ++m) {
    float d = 0.f, q = 0.f;
#pragma unroll
    for (int j = 0; j < 3; ++j) {
#pragma unroll
      for (int c = 0; c < 4; ++c) {
        d += v[m][j][c] * s4[j][c];
        q += v[m][j][c] * v[m][j][c];
      }
    }
    part[m] = d;
    part[10 + m] = q;
  }
  // 64-lane butterfly; 20 independent chains hide ds latency
#pragma unroll
  for (int k = 0; k < 20; ++k) {
#pragma unroll
    for (int off = 32; off >= 1; off >>= 1) part[k] += __shfl_xor(part[k], off);
  }
  const float ss = ((part[0] + part[1]) + (part[2] + part[3])) +
                   ((part[4] + part[5]) + (part[6] + part[7])) +
                   (part[8] + part[9]);  // = dot(sum,sum), exact identity
  const float rc = 1.0f / fmaxf(sqrtf(ss), 10.0f * EPS);
#pragma unroll
  for (int p = 0; p < 3; ++p)
    c8u[n * 192 + lane * 3 + p] =
        pack_fp8x4(s4[p][0] * rc, s4[p][1] * rc, s4[p][2] * rc, s4[p][3] * rc);
#pragma unroll
  for (int m = 0; m < 10; ++m) {
    const float rd = 1.0f / fmaxf(sqrtf(part[10 + m]), EPS);
#pragma unroll
    for (int p = 0; p < 3; ++p)
      a8u[(size_t)(n * 10 + m) * 192 + lane * 3 + p] =
          pack_fp8x4(v[m][p][0] * rd, v[m][p][1] * rd,
                     v[m][p][2] * rd, v[m][p][3] * rd);
  }
  if (lane < 10) {
    const float dot = part[lane], sq = part[10 + lane];
    const float dn = fmaxf(sqrtf(sq), EPS);
    const float en = fmaxf(sqrtf(fmaxf(ss - 2.f * dot + sq, 0.f)) * (1.0f / 9.0f), EPS);
    simown[n * 10 + lane] = ((dot - sq) * (1.0f / 9.0f)) / (dn * en);
  }
}

// ---------------------------------------------------------------------------
// Kernel B (PROMOTED from round-13's measured gemm4, 24.1us): fp8 MFMA GEMM,
// 4 waves, 128x64 tile, counted-vmcnt superstep at 5 blocks/CU (1280 blocks
// x 256 thr = 20 waves/CU TLP). Same XOR-swizzled LDS (both sides, rule #21),
// same vmcnt(3) never-drain loop, bijective XCD swizzle (1280 = 8 x 160).
// Epilogue: diagonal replace with exact fp32 simown + exp-sum atomics
// (no max pass: |w*sim| <= ~10.1; bias b cancels in log_softmax - pick).
// ---------------------------------------------------------------------------
__global__ void __launch_bounds__(256, 5) ge2e_gemm(
    const unsigned char* __restrict__ a8, const unsigned char* __restrict__ c8,
    const float* __restrict__ simown, const float* __restrict__ wp,
    float* __restrict__ rowsum) {
  __shared__ __align__(16) unsigned char As[2][8192];  // 128 rows x 64B
  __shared__ __align__(16) unsigned char Bs[2][4096];  //  64 rows x 64B
  const int t = threadIdx.x;
  const int lane = t & 63, wid = t >> 6;   // 4 waves
  const int bx = blockIdx.x;
  const int wg = (bx & 7) * 160 + (bx >> 3);  // bijective XCD swizzle
  const int rb = wg >> 4, cb = wg & 15;       // 80 rowblocks x 16 colblocks
  const int row0 = rb * 128, col0 = cb * 64;
  const int wm = wid >> 1, wn = wid & 1;      // wave tile: 64 rows x 32 cols
  const int l15 = lane & 15, lg = lane >> 4;
  const int srow = lane >> 2;
  const int sk = (lane & 3) ^ ((lane >> 3) & 3);  // inverse-swizzled src slot

  f32x4 acc[4][2];
#pragma unroll
  for (int i = 0; i < 4; ++i)
#pragma unroll
    for (int j = 0; j < 2; ++j) acc[i][j] = (f32x4){0.f, 0.f, 0.f, 0.f};

  auto STAGE = [&](int buf, int ks) {
#pragma unroll
    for (int j = 0; j < 3; ++j) {
      const int g = wid * 3 + j;  // 0..11: 8 A-segs + 4 B-segs
      if (g < 8) {
        const unsigned char* src =
            a8 + (size_t)(row0 + g * 16 + srow) * 768 + ks * 64 + sk * 16;
        __builtin_amdgcn_global_load_lds(
            (const __attribute__((address_space(1))) unsigned int*)src,
            (__attribute__((address_space(3))) unsigned int*)&As[buf][g * 1024],
            16, 0, 0);
      } else {
        const unsigned char* src =
            c8 + (size_t)(col0 + (g - 8) * 16 + srow) * 768 + ks * 64 + sk * 16;
        __builtin_amdgcn_global_load_lds(
            (const __attribute__((address_space(1))) unsigned int*)src,
            (__attribute__((address_space(3))) unsigned int*)&Bs[buf][(g - 8) * 1024],
            16, 0, 0);
      }
    }
  };
  auto ldA = [&](int buf, int kh, int fr) -> long long {
    const int row = wm * 64 + fr * 16 + l15;
    const int slot = (kh * 2 + (lg >> 1)) ^ ((row >> 1) & 3);
    return *(const long long*)&As[buf][row * 64 + slot * 16 + (lg & 1) * 8];
  };
  auto ldB = [&](int buf, int kh, int fc) -> long long {
    const int row = wn * 32 + fc * 16 + l15;
    const int slot = (kh * 2 + (lg >> 1)) ^ ((row >> 1) & 3);
    return *(const long long*)&Bs[buf][row * 64 + slot * 16 + (lg & 1) * 8];
  };
  auto COMPUTE = [&](int buf) {
#pragma unroll
    for (int kh = 0; kh < 2; ++kh) {   // per-kh frag loads keep VGPR low
      long long af[4], bf[2];
#pragma unroll
      for (int fc = 0; fc < 2; ++fc) bf[fc] = ldB(buf, kh, fc);
#pragma unroll
      for (int fr = 0; fr < 4; ++fr) af[fr] = ldA(buf, kh, fr);
      __builtin_amdgcn_s_setprio(1);
#pragma unroll
      for (int fr = 0; fr < 4; ++fr)
#pragma unroll
        for (int fc = 0; fc < 2; ++fc)
          acc[fr][fc] = __builtin_amdgcn_mfma_f32_16x16x32_fp8_fp8(
              af[fr], bf[fc], acc[fr][fc], 0, 0, 0);
      __builtin_amdgcn_s_setprio(0);
    }
  };

  STAGE(0, 0);
#pragma unroll
  for (int s = 0; s < 12; ++s) {
    if (s < 11) {
      STAGE((s + 1) & 1, s + 1);  // buf free per iter s-1's trailing barrier
      asm volatile("s_waitcnt vmcnt(3)" ::: "memory");  // tile s landed
    } else {
      asm volatile("s_waitcnt vmcnt(0)" ::: "memory");
    }
    __builtin_amdgcn_s_barrier();
    COMPUTE(s & 1);
    if (s < 11) __builtin_amdgcn_s_barrier();  // all waves done with buf[s&1]
  }

  const float wv = wp[0];
  const int R0 = row0 + wm * 64, C0 = col0 + wn * 32;
#pragma unroll
  for (int fr = 0; fr < 4; ++fr) {
#pragma unroll
    for (int r = 0; r < 4; ++r) {
      const int grow = R0 + fr * 16 + lg * 4 + r;
      const int ownc = grow / 10;  // own speaker column
      float sm = 0.f;
#pragma unroll
      for (int fc = 0; fc < 2; ++fc) {
        const int gcol = C0 + fc * 16 + l15;
        float vv = wv * acc[fr][fc][r];
        if (gcol == ownc) vv = wv * simown[grow];
        sm += __expf(vv);
      }
#pragma unroll
      for (int off = 1; off < 16; off <<= 1) sm += __shfl_xor(sm, off, 16);
      if (l15 == 0) atomicAdd(&rowsum[grow], sm);
    }
  }
}

// ---------------------------------------------------------------------------
// Kernel C: loss_i = log(rowsum_i) - w*simown_i; sum over 10240 into d_out.
// ---------------------------------------------------------------------------
__global__ void __launch_bounds__(256) ge2e_final(
    const float* __restrict__ rowsum, const float* __restrict__ simown,
    const float* __restrict__ wp, float* __restrict__ out) {
  const int i = blockIdx.x * 256 + threadIdx.x;  // 0..10239
  const float wv = wp[0];
  float loss = logf(rowsum[i]) - wv * simown[i];
#pragma unroll
  for (int off = 32; off >= 1; off >>= 1) loss += __shfl_xor(loss, off);
  __shared__ float red[4];
  const int lane = threadIdx.x & 63, wid = threadIdx.x >> 6;
  if (lane == 0) red[wid] = loss;
  __syncthreads();
  if (threadIdx.x == 0) atomicAdd(out, red[0] + red[1] + red[2] + red[3]);
}

extern "C" void kernel_launch(void* const* d_in, const int* in_sizes, int n_in,
                              void* d_out, int out_size, void* d_ws, size_t ws_size,
                              hipStream_t stream) {
  (void)in_sizes; (void)n_in; (void)out_size; (void)ws_size;
  const float* dv = (const float*)d_in[0];
  const float* wp = (const float*)d_in[1];
  // d_in[2] (bias b) cancels exactly in -log_softmax[own]; unused.

  unsigned char* a8 = (unsigned char*)d_ws;                         // 7,864,320 B
  unsigned char* c8 = (unsigned char*)d_ws + 7864320;               //   786,432 B
  float* simown = (float*)((char*)d_ws + 8650752);                  //    40,960 B
  float* rowsum = (float*)((char*)d_ws + 8691712);                  //    40,960 B
  float* out = (float*)d_out;

  ge2e_pre<<<256, 256, 0, stream>>>(dv, (unsigned int*)a8, (unsigned int*)c8,
                                    simown, rowsum, out);
  ge2e_gemm<<<1280, 256, 0, stream>>>(a8, c8, simown, wp, rowsum);
  ge2e_final<<<40, 256, 0, stream>>>(rowsum, simown, wp, out);
}

// Round 17
// 40.109 us; speedup vs baseline: 1.0564x; 1.0564x over previous
//
#include <hip/hip_runtime.h>
#include <hip/hip_bf16.h>

#define EPS 1e-6f

typedef __attribute__((ext_vector_type(4))) float f32x4;

// pack 4 floats into 4 fp8-e4m3 bytes (k-order: x->byte0 .. w->byte3)
__device__ inline unsigned int pack_fp8x4(float x, float y, float z, float w) {
  int r = 0;
  r = __builtin_amdgcn_cvt_pk_fp8_f32(x, y, r, false);  // bytes 0,1
  r = __builtin_amdgcn_cvt_pk_fp8_f32(z, w, r, true);   // bytes 2,3
  return (unsigned int)r;
}

// ---------------------------------------------------------------------------
// Kernel A (round-15 winner): ONE WAVE PER SPEAKER.
// 256 blocks x 256 threads (4 speakers/block, lane owns 12 dims).
// Writes a8 (fp8 normalized rows), c8 (fp8 normalized centroids),
// simown (exact fp32), zeroes out[0]. (rowsum zeroing no longer needed:
// gemm now writes per-wave partials with plain stores.)
// ---------------------------------------------------------------------------
__global__ void __launch_bounds__(256) ge2e_pre(
    const float* __restrict__ dv, unsigned int* __restrict__ a8u,
    unsigned int* __restrict__ c8u, float* __restrict__ simown,
    float* __restrict__ out) {
  const int t = threadIdx.x;
  const int wave = t >> 6, lane = t & 63;
  const int n = blockIdx.x * 4 + wave;           // speaker 0..1023
  if (blockIdx.x == 0 && t == 0) out[0] = 0.f;
  const float* base = dv + (size_t)n * 7680 + lane * 12;

  f32x4 v[10][3];
  f32x4 s4[3] = {{0.f, 0.f, 0.f, 0.f}, {0.f, 0.f, 0.f, 0.f}, {0.f, 0.f, 0.f, 0.f}};
#pragma unroll
  for (int m = 0; m < 10; ++m)
#pragma unroll
    for (int j = 0; j < 3; ++j) {
      v[m][j] = *reinterpret_cast<const f32x4*>(base + m * 768 + j * 4);
      s4[j] += v[m][j];
    }
  float part[20];
#pragma unroll
  for (int m = 0; m < 10; ++m) {
    float d = 0.f, q = 0.f;
#pragma unroll
    for (int j = 0; j < 3; ++j) {
#pragma unroll
      for (int c = 0; c < 4; ++c) {
        d += v[m][j][c] * s4[j][c];
        q += v[m][j][c] * v[m][j][c];
      }
    }
    part[m] = d;
    part[10 + m] = q;
  }
  // 64-lane butterfly; 20 independent chains hide ds latency
#pragma unroll
  for (int k = 0; k < 20; ++k) {
#pragma unroll
    for (int off = 32; off >= 1; off >>= 1) part[k] += __shfl_xor(part[k], off);
  }
  const float ss = ((part[0] + part[1]) + (part[2] + part[3])) +
                   ((part[4] + part[5]) + (part[6] + part[7])) +
                   (part[8] + part[9]);  // = dot(sum,sum), exact identity
  const float rc = 1.0f / fmaxf(sqrtf(ss), 10.0f * EPS);
#pragma unroll
  for (int p = 0; p < 3; ++p)
    c8u[n * 192 + lane * 3 + p] =
        pack_fp8x4(s4[p][0] * rc, s4[p][1] * rc, s4[p][2] * rc, s4[p][3] * rc);
#pragma unroll
  for (int m = 0; m < 10; ++m) {
    const float rd = 1.0f / fmaxf(sqrtf(part[10 + m]), EPS);
#pragma unroll
    for (int p = 0; p < 3; ++p)
      a8u[(size_t)(n * 10 + m) * 192 + lane * 3 + p] =
          pack_fp8x4(v[m][p][0] * rd, v[m][p][1] * rd,
                     v[m][p][2] * rd, v[m][p][3] * rd);
  }
  if (lane < 10) {
    const float dot = part[lane], sq = part[10 + lane];
    const float dn = fmaxf(sqrtf(sq), EPS);
    const float en = fmaxf(sqrtf(fmaxf(ss - 2.f * dot + sq, 0.f)) * (1.0f / 9.0f), EPS);
    simown[n * 10 + lane] = ((dot - sq) * (1.0f / 9.0f)) / (dn * en);
  }
}

// ---------------------------------------------------------------------------
// Kernel B: fp8 MFMA GEMM, round-11/15 best-measured structure (tile 320x64,
// 8 waves 4Mx2N, counted-vmcnt superstep, 512 blocks = 2/CU, XOR-swizzled
// LDS both sides, bijective XCD swizzle). EPILOGUE CHANGE vs r15: per-wave
// exp-sum partials are written with PLAIN STORES to rowsumP[row*32+cb*2+wn]
// (exactly one writer wave per slot -- no 16-way atomic contention in the
// kernel tail). ge2e_final sums the 32 partials per row.
// ---------------------------------------------------------------------------
__global__ void __launch_bounds__(512, 4) ge2e_gemm(
    const unsigned char* __restrict__ a8, const unsigned char* __restrict__ c8,
    const float* __restrict__ simown, const float* __restrict__ wp,
    float* __restrict__ rowsumP) {
  __shared__ __align__(16) unsigned char As[2][20480];  // [buf] 320 rows x 64B
  __shared__ __align__(16) unsigned char Bs[2][4096];   // [buf]  64 rows x 64B
  const int t = threadIdx.x;
  const int lane = t & 63, wid = t >> 6;
  const int bx = blockIdx.x;
  const int wg = (bx & 7) * 64 + (bx >> 3);  // bijective XCD swizzle, 512=8x64
  const int rb = wg >> 4, cb = wg & 15;
  const int row0 = rb * 320, col0 = cb * 64;
  const int wm = wid >> 1, wn = wid & 1;     // wave tile: 80 rows x 32 cols
  const int l15 = lane & 15, lg = lane >> 4;
  const int srow = lane >> 2;
  const int sk = (lane & 3) ^ ((lane >> 3) & 3);  // inverse-swizzled src slot

  f32x4 acc[5][2];
#pragma unroll
  for (int i = 0; i < 5; ++i)
#pragma unroll
    for (int j = 0; j < 2; ++j) acc[i][j] = (f32x4){0.f, 0.f, 0.f, 0.f};

  auto STAGE = [&](int buf, int ks) {
#pragma unroll
    for (int j = 0; j < 3; ++j) {
      const int g = wid * 3 + j;  // 0..23, wave-uniform
      if (g < 20) {               // A: rows g*16..g*16+15
        const unsigned char* src =
            a8 + (size_t)(row0 + g * 16 + srow) * 768 + ks * 64 + sk * 16;
        __builtin_amdgcn_global_load_lds(
            (const __attribute__((address_space(1))) unsigned int*)src,
            (__attribute__((address_space(3))) unsigned int*)&As[buf][g * 1024],
            16, 0, 0);
      } else {                    // B: rows (g-20)*16..+15
        const unsigned char* src =
            c8 + (size_t)(col0 + (g - 20) * 16 + srow) * 768 + ks * 64 + sk * 16;
        __builtin_amdgcn_global_load_lds(
            (const __attribute__((address_space(1))) unsigned int*)src,
            (__attribute__((address_space(3))) unsigned int*)&Bs[buf][(g - 20) * 1024],
            16, 0, 0);
      }
    }
  };
  auto ldA = [&](int buf, int kh, int fr) -> long long {
    const int row = wm * 80 + fr * 16 + l15;
    const int slot = (kh * 2 + (lg >> 1)) ^ ((row >> 1) & 3);
    return *(const long long*)&As[buf][row * 64 + slot * 16 + (lg & 1) * 8];
  };
  auto ldB = [&](int buf, int kh, int fc) -> long long {
    const int row = wn * 32 + fc * 16 + l15;
    const int slot = (kh * 2 + (lg >> 1)) ^ ((row >> 1) & 3);
    return *(const long long*)&Bs[buf][row * 64 + slot * 16 + (lg & 1) * 8];
  };
  auto COMPUTE = [&](int buf) {
    long long af[5][2], bf[2][2];
#pragma unroll
    for (int fc = 0; fc < 2; ++fc)
#pragma unroll
      for (int kh = 0; kh < 2; ++kh) bf[fc][kh] = ldB(buf, kh, fc);
#pragma unroll
    for (int fr = 0; fr < 5; ++fr)
#pragma unroll
      for (int kh = 0; kh < 2; ++kh) af[fr][kh] = ldA(buf, kh, fr);
    __builtin_amdgcn_s_setprio(1);
#pragma unroll
    for (int kh = 0; kh < 2; ++kh)
#pragma unroll
      for (int fr = 0; fr < 5; ++fr)
#pragma unroll
        for (int fc = 0; fc < 2; ++fc)
          acc[fr][fc] = __builtin_amdgcn_mfma_f32_16x16x32_fp8_fp8(
              af[fr][kh], bf[fc][kh], acc[fr][fc], 0, 0, 0);
    __builtin_amdgcn_s_setprio(0);
  };

  STAGE(0, 0);
#pragma unroll
  for (int s = 0; s < 12; ++s) {
    if (s < 11) {
      STAGE((s + 1) & 1, s + 1);  // buf free per iter s-1's trailing barrier
      asm volatile("s_waitcnt vmcnt(3)" ::: "memory");  // tile s landed
    } else {
      asm volatile("s_waitcnt vmcnt(0)" ::: "memory");
    }
    __builtin_amdgcn_s_barrier();
    COMPUTE(s & 1);
    if (s < 11) __builtin_amdgcn_s_barrier();  // all waves done with buf[s&1]
  }

  // Epilogue: vv = w*cos (diagonal: fp32 sim_own); per-wave partial
  // rowsumP[grow*32 + cb*2 + wn] = sum over this wave's 32 cols of exp(vv).
  // |vv| <= ~10.1 -> exp fp32-safe without max subtraction; bias b cancels.
  const float wv = wp[0];
  const int R0 = row0 + wm * 80, C0 = col0 + wn * 32;
#pragma unroll
  for (int fr = 0; fr < 5; ++fr) {
#pragma unroll
    for (int r = 0; r < 4; ++r) {
      const int grow = R0 + fr * 16 + lg * 4 + r;
      const int ownc = grow / 10;  // own speaker column
      float sm = 0.f;
#pragma unroll
      for (int fc = 0; fc < 2; ++fc) {
        const int gcol = C0 + fc * 16 + l15;
        float vv = wv * acc[fr][fc][r];
        if (gcol == ownc) vv = wv * simown[grow];
        sm += __expf(vv);
      }
#pragma unroll
      for (int off = 1; off < 16; off <<= 1) sm += __shfl_xor(sm, off, 16);
      if (l15 == 0) rowsumP[(size_t)grow * 32 + cb * 2 + wn] = sm;  // plain store
    }
  }
}

// ---------------------------------------------------------------------------
// Kernel C: sum the 32 partials per row (128 B coalesced per thread),
// loss_i = log(rowsum_i) - w*simown_i; sum over 10240 into d_out.
// ---------------------------------------------------------------------------
__global__ void __launch_bounds__(256) ge2e_final(
    const float* __restrict__ rowsumP, const float* __restrict__ simown,
    const float* __restrict__ wp, float* __restrict__ out) {
  const int i = blockIdx.x * 256 + threadIdx.x;  // 0..10239
  const float wv = wp[0];
  const f32x4* p = reinterpret_cast<const f32x4*>(rowsumP + (size_t)i * 32);
  float s = 0.f;
#pragma unroll
  for (int q = 0; q < 8; ++q) {
    const f32x4 v = p[q];
    s += (v[0] + v[1]) + (v[2] + v[3]);
  }
  float loss = logf(s) - wv * simown[i];
#pragma unroll
  for (int off = 32; off >= 1; off >>= 1) loss += __shfl_xor(loss, off);
  __shared__ float red[4];
  const int lane = threadIdx.x & 63, wid = threadIdx.x >> 6;
  if (lane == 0) red[wid] = loss;
  __syncthreads();
  if (threadIdx.x == 0) atomicAdd(out, red[0] + red[1] + red[2] + red[3]);
}

extern "C" void kernel_launch(void* const* d_in, const int* in_sizes, int n_in,
                              void* d_out, int out_size, void* d_ws, size_t ws_size,
                              hipStream_t stream) {
  (void)in_sizes; (void)n_in; (void)out_size; (void)ws_size;
  const float* dv = (const float*)d_in[0];
  const float* wp = (const float*)d_in[1];
  // d_in[2] (bias b) cancels exactly in -log_softmax[own]; unused.

  unsigned char* a8 = (unsigned char*)d_ws;                         // 7,864,320 B
  unsigned char* c8 = (unsigned char*)d_ws + 7864320;               //   786,432 B
  float* simown  = (float*)((char*)d_ws + 8650752);                 //    40,960 B
  float* rowsumP = (float*)((char*)d_ws + 8691712);                 // 1,310,720 B
  float* out = (float*)d_out;

  ge2e_pre<<<256, 256, 0, stream>>>(dv, (unsigned int*)a8, (unsigned int*)c8,
                                    simown, out);
  ge2e_gemm<<<512, 512, 0, stream>>>(a8, c8, simown, wp, rowsumP);
  ge2e_final<<<40, 256, 0, stream>>>(rowsumP, simown, wp, out);
}